// Round 6
// baseline (233.743 us; speedup 1.0000x reference)
//
#include <hip/hip_runtime.h>
#include <hip/hip_bf16.h>

#define N_NODES 50000
#define N_EDGES 800000
#define IN_DIM 128
#define OUT_DIM 64
#define NEG_SLOPE 0.01f
#define NEG_INF (-3.0e38f)

#define N_I4 (N_NODES / 4)          // 12500 int4 elements
#define N_SBLK ((N_I4 + 255) / 256) // 49 scan blocks
#define Z_BLOCKS 1024
#define E_I4 (N_EDGES / 4)           // 200000
#define HIST_BLOCKS ((E_I4 + 255) / 256)

__device__ __forceinline__ float rlanef(float v, int l) {
  return __uint_as_float(__builtin_amdgcn_readlane(__float_as_uint(v), l));
}
__device__ __forceinline__ int rlanei(int v, int l) {
  return __builtin_amdgcn_readlane(v, l);
}

// ---------------------------------------------------------------------------
// Stage 1 (fused). Blocks [0, Z_BLOCKS): wave-per-node z GEMM.
//   lane j holds fcw[j][0..128) in 128 VGPRs (elementwise init -> SROA keeps
//   it in registers; the R1/R4 float4-cast version silently went to scratch).
//   Feature row is wave-uniform -> compiler emits s_load batches (scalar
//   pipe, no LDS, no VMEM); 128 v_fma_f32 with SGPR operand per node.
//   z stored as bf16 (halves gather traffic in gat_agg); asrc/adst stay fp32
//   computed from the fp32 accumulator.
// Blocks [Z_BLOCKS, ...): dst histogram (int4-vectorized).
// ---------------------------------------------------------------------------
__global__ __launch_bounds__(256, 3) void gat_z_hist(
    const float* __restrict__ feat, const float* __restrict__ fcw,
    const float* __restrict__ attnw, __hip_bfloat16* __restrict__ z,
    float* __restrict__ asrc, float* __restrict__ adst,
    const int* __restrict__ dst, int* __restrict__ counts) {
  if (blockIdx.x >= Z_BLOCKS) {
    int t = (blockIdx.x - Z_BLOCKS) * 256 + threadIdx.x;
    if (t < E_I4) {
      int4 d = ((const int4*)dst)[t];
      atomicAdd(counts + d.x, 1);
      atomicAdd(counts + d.y, 1);
      atomicAdd(counts + d.z, 1);
      atomicAdd(counts + d.w, 1);
    }
    return;
  }

  const int lane = threadIdx.x & 63;
  const int wave = (blockIdx.x * blockDim.x + threadIdx.x) >> 6;
  const int nwaves = Z_BLOCKS * 4;

  // lane j: full weight row in VGPRs (elementwise -> SROA-safe)
  float w[IN_DIM];
  {
    const float* wr = fcw + (size_t)lane * IN_DIM;
#pragma unroll
    for (int i = 0; i < IN_DIM; ++i) w[i] = wr[i];
  }
  const float aws = attnw[lane];
  const float awd = attnw[OUT_DIM + lane];

  for (int node = wave; node < N_NODES; node += nwaves) {
    const int ns = __builtin_amdgcn_readfirstlane(node);
    const float* __restrict__ fr = feat + (size_t)ns * IN_DIM;  // uniform -> s_load
    float a0 = 0.f, a1 = 0.f, a2 = 0.f, a3 = 0.f;
#pragma unroll
    for (int k = 0; k < IN_DIM; k += 4) {
      a0 = fmaf(fr[k + 0], w[k + 0], a0);
      a1 = fmaf(fr[k + 1], w[k + 1], a1);
      a2 = fmaf(fr[k + 2], w[k + 2], a2);
      a3 = fmaf(fr[k + 3], w[k + 3], a3);
    }
    const float acc = (a0 + a1) + (a2 + a3);
    z[(size_t)ns * OUT_DIM + lane] = __float2bfloat16(acc);

    float s = acc * aws, d = acc * awd;
#pragma unroll
    for (int off = 32; off; off >>= 1) {
      s += __shfl_xor(s, off, 64);
      d += __shfl_xor(d, off, 64);
    }
    if (lane == 0) {
      asrc[ns] = s;
      adst[ns] = d;
    }
  }
}

// ---------------------------------------------------------------------------
// Hierarchical exclusive scan (3 kernels) + bucket scatter.
// ---------------------------------------------------------------------------
__global__ __launch_bounds__(256) void gat_scan_partial(
    const int* __restrict__ counts, int* __restrict__ bsum) {
  const int lane = threadIdx.x & 63;
  const int wid = threadIdx.x >> 6;
  int i4 = blockIdx.x * 256 + threadIdx.x;
  int4 c = (i4 < N_I4) ? ((const int4*)counts)[i4] : make_int4(0, 0, 0, 0);
  int s = c.x + c.y + c.z + c.w;
#pragma unroll
  for (int off = 32; off; off >>= 1) s += __shfl_xor(s, off, 64);
  __shared__ int ws[4];
  if (lane == 0) ws[wid] = s;
  __syncthreads();
  if (threadIdx.x == 0) bsum[blockIdx.x] = ws[0] + ws[1] + ws[2] + ws[3];
}

__global__ __launch_bounds__(64) void gat_scan_base(
    const int* __restrict__ bsum, int* __restrict__ bbase,
    int* __restrict__ offsets) {
  const int t = threadIdx.x;
  int v = (t < N_SBLK) ? bsum[t] : 0;
  int incl = v;
#pragma unroll
  for (int off = 1; off < 64; off <<= 1) {
    int u = __shfl_up(incl, off, 64);
    if (t >= off) incl += u;
  }
  if (t < N_SBLK) bbase[t] = incl - v;
  if (t == 63) offsets[N_NODES] = incl;  // == N_EDGES
}

__global__ __launch_bounds__(256) void gat_scan_final(
    const int* __restrict__ counts, const int* __restrict__ bbase,
    int* __restrict__ offsets, int* __restrict__ cursor) {
  const int lane = threadIdx.x & 63;
  const int wid = threadIdx.x >> 6;
  int i4 = blockIdx.x * 256 + threadIdx.x;
  int4 c = (i4 < N_I4) ? ((const int4*)counts)[i4] : make_int4(0, 0, 0, 0);
  int s = c.x + c.y + c.z + c.w;
  int incl = s;
#pragma unroll
  for (int off = 1; off < 64; off <<= 1) {
    int u = __shfl_up(incl, off, 64);
    if (lane >= off) incl += u;
  }
  __shared__ int ws[4];
  if (lane == 63) ws[wid] = incl;
  __syncthreads();
  int wb = 0;
#pragma unroll
  for (int k = 0; k < 4; ++k)
    if (k < wid) wb += ws[k];
  int ex = bbase[blockIdx.x] + wb + (incl - s);
  int4 o;
  o.x = ex;
  o.y = o.x + c.x;
  o.z = o.y + c.y;
  o.w = o.z + c.z;
  if (i4 < N_I4) {
    ((int4*)offsets)[i4] = o;
    ((int4*)cursor)[i4] = o;
  }
}

// int4-vectorized bucket scatter: 4 independent atomic+store chains/thread
__global__ __launch_bounds__(256) void gat_escatter(
    const int* __restrict__ src, const int* __restrict__ dst,
    int* __restrict__ cursor, int* __restrict__ ssorted) {
  int t = blockIdx.x * blockDim.x + threadIdx.x;
  if (t >= E_I4) return;
  int4 s = ((const int4*)src)[t];
  int4 d = ((const int4*)dst)[t];
  int p0 = atomicAdd(cursor + d.x, 1);
  int p1 = atomicAdd(cursor + d.y, 1);
  int p2 = atomicAdd(cursor + d.z, 1);
  int p3 = atomicAdd(cursor + d.w, 1);
  ssorted[p0] = s.x;
  ssorted[p1] = s.y;
  ssorted[p2] = s.z;
  ssorted[p3] = s.w;
}

// ---------------------------------------------------------------------------
// Aggregation: one wave per dst node, online softmax, readlane broadcasts,
// 4-wide unrolled bf16 z-row gather-accumulate. No atomics.
// ---------------------------------------------------------------------------
__global__ __launch_bounds__(256) void gat_agg(
    const __hip_bfloat16* __restrict__ z, const float* __restrict__ asrc,
    const float* __restrict__ adst, const int* __restrict__ offsets,
    const int* __restrict__ ssorted, float* __restrict__ out) {
  const int lane = threadIdx.x & 63;
  const int node = (blockIdx.x * blockDim.x + threadIdx.x) >> 6;
  if (node >= N_NODES) return;
  const int o0 = offsets[node];
  const int o1 = offsets[node + 1];
  if (o0 == o1) {  // no incoming edges: elu(0/1) = 0
    out[(size_t)node * OUT_DIM + lane] = 0.f;
    return;
  }
  const float ad = adst[node];

  float m = NEG_INF, dsum = 0.f;
  float acc0 = 0.f, acc1 = 0.f, acc2 = 0.f, acc3 = 0.f;

  for (int base = o0; base < o1; base += 64) {
    const int cnt = min(64, o1 - base);
    int s = 0;
    float ev = NEG_INF;
    if (lane < cnt) {
      s = ssorted[base + lane];
      float v = asrc[s] + ad;
      ev = v > 0.f ? v : NEG_SLOPE * v;
    }
    float cm = ev;
#pragma unroll
    for (int off = 32; off; off >>= 1) cm = fmaxf(cm, __shfl_xor(cm, off, 64));
    const float nm = fmaxf(m, cm);
    const float scale = __expf(m - nm);  // first chunk: exp(-inf) = 0
    dsum *= scale;
    acc0 *= scale; acc1 *= scale; acc2 *= scale; acc3 *= scale;
    m = nm;

    float w = (lane < cnt) ? __expf(ev - m) : 0.f;
    dsum += w;

    int j = 0;
    for (; j + 4 <= cnt; j += 4) {
      const int s0 = rlanei(s, j + 0), s1 = rlanei(s, j + 1);
      const int s2 = rlanei(s, j + 2), s3 = rlanei(s, j + 3);
      const float w0 = rlanef(w, j + 0), w1 = rlanef(w, j + 1);
      const float w2 = rlanef(w, j + 2), w3 = rlanef(w, j + 3);
      const float z0 = __bfloat162float(z[(size_t)s0 * OUT_DIM + lane]);
      const float z1 = __bfloat162float(z[(size_t)s1 * OUT_DIM + lane]);
      const float z2 = __bfloat162float(z[(size_t)s2 * OUT_DIM + lane]);
      const float z3 = __bfloat162float(z[(size_t)s3 * OUT_DIM + lane]);
      acc0 = fmaf(w0, z0, acc0);
      acc1 = fmaf(w1, z1, acc1);
      acc2 = fmaf(w2, z2, acc2);
      acc3 = fmaf(w3, z3, acc3);
    }
    for (; j < cnt; ++j) {
      const int sj = rlanei(s, j);
      const float wj = rlanef(w, j);
      acc0 = fmaf(wj, __bfloat162float(z[(size_t)sj * OUT_DIM + lane]), acc0);
    }
  }
  float acc = (acc0 + acc1) + (acc2 + acc3);
#pragma unroll
  for (int off = 32; off; off >>= 1) dsum += __shfl_xor(dsum, off, 64);

  const float h = acc / (dsum > 0.f ? dsum : 1.f);
  out[(size_t)node * OUT_DIM + lane] = h > 0.f ? h : expm1f(h);
}

// ---------------------------------------------------------------------------
extern "C" void kernel_launch(void* const* d_in, const int* in_sizes, int n_in,
                              void* d_out, int out_size, void* d_ws, size_t ws_size,
                              hipStream_t stream) {
  const float* feat  = (const float*)d_in[0];
  const float* fcw   = (const float*)d_in[1];
  const float* attnw = (const float*)d_in[2];
  const int* src     = (const int*)d_in[3];
  const int* dst     = (const int*)d_in[4];
  float* out = (float*)d_out;

  char* ws = (char*)d_ws;
  __hip_bfloat16* z = (__hip_bfloat16*)ws;
  ws += (size_t)N_NODES * OUT_DIM * sizeof(__hip_bfloat16);  // 6.4 MB
  float* asrc = (float*)ws;   ws += (size_t)N_NODES * sizeof(float);
  float* adst = (float*)ws;   ws += (size_t)N_NODES * sizeof(float);
  int* counts = (int*)ws;     ws += (size_t)N_NODES * sizeof(int);
  int* cursor = (int*)ws;     ws += (size_t)N_NODES * sizeof(int);
  int* offsets = (int*)ws;    ws += (size_t)(N_NODES + 4) * sizeof(int);  // padded
  int* bsum = (int*)ws;       ws += 64 * sizeof(int);
  int* bbase = (int*)ws;      ws += 64 * sizeof(int);
  int* ssorted = (int*)ws;    ws += (size_t)N_EDGES * sizeof(int);        // 3.2 MB

  hipMemsetAsync(counts, 0, (size_t)N_NODES * sizeof(int), stream);

  gat_z_hist<<<Z_BLOCKS + HIST_BLOCKS, 256, 0, stream>>>(feat, fcw, attnw, z,
                                                         asrc, adst, dst, counts);
  gat_scan_partial<<<N_SBLK, 256, 0, stream>>>(counts, bsum);
  gat_scan_base<<<1, 64, 0, stream>>>(bsum, bbase, offsets);
  gat_scan_final<<<N_SBLK, 256, 0, stream>>>(counts, bbase, offsets, cursor);
  gat_escatter<<<HIST_BLOCKS, 256, 0, stream>>>(src, dst, cursor, ssorted);
  gat_agg<<<(N_NODES * 64 + 255) / 256, 256, 0, stream>>>(z, asrc, adst, offsets, ssorted, out);
}

// Round 7
// 202.886 us; speedup vs baseline: 1.1521x; 1.1521x over previous
//
#include <hip/hip_runtime.h>
#include <hip/hip_bf16.h>

#define N_NODES 50000
#define N_EDGES 800000
#define IN_DIM 128
#define OUT_DIM 64
#define NEG_SLOPE 0.01f
#define NEG_INF (-3.0e38f)

#define N_I4 (N_NODES / 4)          // 12500 int4 elements
#define N_SBLK ((N_I4 + 255) / 256) // 49 scan blocks
#define N_STRIPS (N_NODES / 16)      // 3125 16-node MFMA strips
#define Z_BLOCKS ((N_STRIPS + 3) / 4) // 782 (4 waves/block, 1 strip/wave)
#define E_I4 (N_EDGES / 4)           // 200000
#define HIST_BLOCKS ((E_I4 + 255) / 256)

typedef __bf16 bf16x8 __attribute__((ext_vector_type(8)));
typedef float f32x4 __attribute__((ext_vector_type(4)));

__device__ __forceinline__ float rlanef(float v, int l) {
  return __uint_as_float(__builtin_amdgcn_readlane(__float_as_uint(v), l));
}
__device__ __forceinline__ int rlanei(int v, int l) {
  return __builtin_amdgcn_readlane(v, l);
}

__device__ __forceinline__ unsigned short f2bf_us(float f) {
  __hip_bfloat16 h = __float2bfloat16(f);  // RNE
  return *reinterpret_cast<unsigned short*>(&h);
}
// pack 8 floats (two float4) -> v8bf16 fragment
__device__ __forceinline__ bf16x8 pack_bf16(float4 lo, float4 hi) {
  union { bf16x8 v; unsigned short u[8]; } r;
  r.u[0] = f2bf_us(lo.x); r.u[1] = f2bf_us(lo.y);
  r.u[2] = f2bf_us(lo.z); r.u[3] = f2bf_us(lo.w);
  r.u[4] = f2bf_us(hi.x); r.u[5] = f2bf_us(hi.y);
  r.u[6] = f2bf_us(hi.z); r.u[7] = f2bf_us(hi.w);
  return r.v;
}

// ---------------------------------------------------------------------------
// Stage 1 (fused). Blocks [0, Z_BLOCKS): MFMA z-GEMM, one 16-node strip per
// wave. A-frag: A[m=lane&15][k=quad*8+j] (feat row per lane, no LDS, no
// broadcast). B-frags: fcw rows (lane&15)+16t, 16 frags = 64 VGPRs, loaded
// once. C/D: col=lane&15, row=quad*4+reg (HW-verified layout). Fused
// asrc/adst via quad-group shfl reduction. z stored bf16.
// Blocks [Z_BLOCKS, ...): dst histogram (int4-vectorized).
// ---------------------------------------------------------------------------
__global__ __launch_bounds__(256) void gat_z_hist(
    const float* __restrict__ feat, const float* __restrict__ fcw,
    const float* __restrict__ attnw, __hip_bfloat16* __restrict__ z,
    float* __restrict__ asrc, float* __restrict__ adst,
    const int* __restrict__ dst, int* __restrict__ counts) {
  if (blockIdx.x >= Z_BLOCKS) {
    int t = (blockIdx.x - Z_BLOCKS) * 256 + threadIdx.x;
    if (t < E_I4) {
      int4 d = ((const int4*)dst)[t];
      atomicAdd(counts + d.x, 1);
      atomicAdd(counts + d.y, 1);
      atomicAdd(counts + d.z, 1);
      atomicAdd(counts + d.w, 1);
    }
    return;
  }

  const int lane = threadIdx.x & 63;
  const int m = lane & 15;
  const int quad = lane >> 4;
  const int wv = blockIdx.x * 4 + (threadIdx.x >> 6);
  if (wv >= N_STRIPS) return;
  const int n0 = wv * 16;

  // B fragments: bfrag[t][c][j] = fcw[m+16t][c*32 + quad*8 + j]
  bf16x8 bfrag[4][4];
#pragma unroll
  for (int t = 0; t < 4; ++t) {
    const float* wr = fcw + (size_t)(m + 16 * t) * IN_DIM + quad * 8;
#pragma unroll
    for (int c = 0; c < 4; ++c) {
      float4 lo = *(const float4*)(wr + c * 32);
      float4 hi = *(const float4*)(wr + c * 32 + 4);
      bfrag[t][c] = pack_bf16(lo, hi);
    }
  }

  f32x4 acc[4] = {{0.f, 0.f, 0.f, 0.f}, {0.f, 0.f, 0.f, 0.f},
                  {0.f, 0.f, 0.f, 0.f}, {0.f, 0.f, 0.f, 0.f}};
  const float* ar = feat + (size_t)(n0 + m) * IN_DIM + quad * 8;
#pragma unroll
  for (int c = 0; c < 4; ++c) {
    float4 lo = *(const float4*)(ar + c * 32);
    float4 hi = *(const float4*)(ar + c * 32 + 4);
    const bf16x8 af = pack_bf16(lo, hi);
#pragma unroll
    for (int t = 0; t < 4; ++t)
      acc[t] = __builtin_amdgcn_mfma_f32_16x16x32_bf16(af, bfrag[t][c],
                                                       acc[t], 0, 0, 0);
  }

  // store z: acc[t][r] = z[n0 + quad*4 + r][m + 16t]
#pragma unroll
  for (int t = 0; t < 4; ++t)
#pragma unroll
    for (int r = 0; r < 4; ++r)
      z[(size_t)(n0 + quad * 4 + r) * OUT_DIM + m + 16 * t] =
          __float2bfloat16(acc[t][r]);

  // fused a_src/a_dst: per-lane partial over its 4 cols, then quad-group sum
  float aws[4], awd[4];
#pragma unroll
  for (int t = 0; t < 4; ++t) {
    aws[t] = attnw[m + 16 * t];
    awd[t] = attnw[OUT_DIM + m + 16 * t];
  }
  float ps[4], pd[4];
#pragma unroll
  for (int r = 0; r < 4; ++r) {
    float s = 0.f, d = 0.f;
#pragma unroll
    for (int t = 0; t < 4; ++t) {
      s = fmaf(acc[t][r], aws[t], s);
      d = fmaf(acc[t][r], awd[t], d);
    }
    ps[r] = s;
    pd[r] = d;
  }
#pragma unroll
  for (int off = 1; off < 16; off <<= 1) {
#pragma unroll
    for (int r = 0; r < 4; ++r) {
      ps[r] += __shfl_xor(ps[r], off, 64);
      pd[r] += __shfl_xor(pd[r], off, 64);
    }
  }
  if (m == 0) {
#pragma unroll
    for (int r = 0; r < 4; ++r) {
      asrc[n0 + quad * 4 + r] = ps[r];
      adst[n0 + quad * 4 + r] = pd[r];
    }
  }
}

// ---------------------------------------------------------------------------
// Hierarchical exclusive scan (3 kernels) + bucket scatter.
// ---------------------------------------------------------------------------
__global__ __launch_bounds__(256) void gat_scan_partial(
    const int* __restrict__ counts, int* __restrict__ bsum) {
  const int lane = threadIdx.x & 63;
  const int wid = threadIdx.x >> 6;
  int i4 = blockIdx.x * 256 + threadIdx.x;
  int4 c = (i4 < N_I4) ? ((const int4*)counts)[i4] : make_int4(0, 0, 0, 0);
  int s = c.x + c.y + c.z + c.w;
#pragma unroll
  for (int off = 32; off; off >>= 1) s += __shfl_xor(s, off, 64);
  __shared__ int ws[4];
  if (lane == 0) ws[wid] = s;
  __syncthreads();
  if (threadIdx.x == 0) bsum[blockIdx.x] = ws[0] + ws[1] + ws[2] + ws[3];
}

__global__ __launch_bounds__(64) void gat_scan_base(
    const int* __restrict__ bsum, int* __restrict__ bbase,
    int* __restrict__ offsets) {
  const int t = threadIdx.x;
  int v = (t < N_SBLK) ? bsum[t] : 0;
  int incl = v;
#pragma unroll
  for (int off = 1; off < 64; off <<= 1) {
    int u = __shfl_up(incl, off, 64);
    if (t >= off) incl += u;
  }
  if (t < N_SBLK) bbase[t] = incl - v;
  if (t == 63) offsets[N_NODES] = incl;  // == N_EDGES
}

__global__ __launch_bounds__(256) void gat_scan_final(
    const int* __restrict__ counts, const int* __restrict__ bbase,
    int* __restrict__ offsets, int* __restrict__ cursor) {
  const int lane = threadIdx.x & 63;
  const int wid = threadIdx.x >> 6;
  int i4 = blockIdx.x * 256 + threadIdx.x;
  int4 c = (i4 < N_I4) ? ((const int4*)counts)[i4] : make_int4(0, 0, 0, 0);
  int s = c.x + c.y + c.z + c.w;
  int incl = s;
#pragma unroll
  for (int off = 1; off < 64; off <<= 1) {
    int u = __shfl_up(incl, off, 64);
    if (lane >= off) incl += u;
  }
  __shared__ int ws[4];
  if (lane == 63) ws[wid] = incl;
  __syncthreads();
  int wb = 0;
#pragma unroll
  for (int k = 0; k < 4; ++k)
    if (k < wid) wb += ws[k];
  int ex = bbase[blockIdx.x] + wb + (incl - s);
  int4 o;
  o.x = ex;
  o.y = o.x + c.x;
  o.z = o.y + c.y;
  o.w = o.z + c.z;
  if (i4 < N_I4) {
    ((int4*)offsets)[i4] = o;
    ((int4*)cursor)[i4] = o;
  }
}

// int4-vectorized bucket scatter: 4 independent atomic+store chains/thread
__global__ __launch_bounds__(256) void gat_escatter(
    const int* __restrict__ src, const int* __restrict__ dst,
    int* __restrict__ cursor, int* __restrict__ ssorted) {
  int t = blockIdx.x * blockDim.x + threadIdx.x;
  if (t >= E_I4) return;
  int4 s = ((const int4*)src)[t];
  int4 d = ((const int4*)dst)[t];
  int p0 = atomicAdd(cursor + d.x, 1);
  int p1 = atomicAdd(cursor + d.y, 1);
  int p2 = atomicAdd(cursor + d.z, 1);
  int p3 = atomicAdd(cursor + d.w, 1);
  ssorted[p0] = s.x;
  ssorted[p1] = s.y;
  ssorted[p2] = s.z;
  ssorted[p3] = s.w;
}

// ---------------------------------------------------------------------------
// Aggregation: one wave per dst node, online softmax, readlane broadcasts,
// 4-wide unrolled bf16 z-row gather-accumulate. No atomics.
// ---------------------------------------------------------------------------
__global__ __launch_bounds__(256) void gat_agg(
    const __hip_bfloat16* __restrict__ z, const float* __restrict__ asrc,
    const float* __restrict__ adst, const int* __restrict__ offsets,
    const int* __restrict__ ssorted, float* __restrict__ out) {
  const int lane = threadIdx.x & 63;
  const int node = (blockIdx.x * blockDim.x + threadIdx.x) >> 6;
  if (node >= N_NODES) return;
  const int o0 = offsets[node];
  const int o1 = offsets[node + 1];
  if (o0 == o1) {  // no incoming edges: elu(0/1) = 0
    out[(size_t)node * OUT_DIM + lane] = 0.f;
    return;
  }
  const float ad = adst[node];

  float m = NEG_INF, dsum = 0.f;
  float acc0 = 0.f, acc1 = 0.f, acc2 = 0.f, acc3 = 0.f;

  for (int base = o0; base < o1; base += 64) {
    const int cnt = min(64, o1 - base);
    int s = 0;
    float ev = NEG_INF;
    if (lane < cnt) {
      s = ssorted[base + lane];
      float v = asrc[s] + ad;
      ev = v > 0.f ? v : NEG_SLOPE * v;
    }
    float cm = ev;
#pragma unroll
    for (int off = 32; off; off >>= 1) cm = fmaxf(cm, __shfl_xor(cm, off, 64));
    const float nm = fmaxf(m, cm);
    const float scale = __expf(m - nm);  // first chunk: exp(-inf) = 0
    dsum *= scale;
    acc0 *= scale; acc1 *= scale; acc2 *= scale; acc3 *= scale;
    m = nm;

    float w = (lane < cnt) ? __expf(ev - m) : 0.f;
    dsum += w;

    int j = 0;
    for (; j + 4 <= cnt; j += 4) {
      const int s0 = rlanei(s, j + 0), s1 = rlanei(s, j + 1);
      const int s2 = rlanei(s, j + 2), s3 = rlanei(s, j + 3);
      const float w0 = rlanef(w, j + 0), w1 = rlanef(w, j + 1);
      const float w2 = rlanef(w, j + 2), w3 = rlanef(w, j + 3);
      const float z0 = __bfloat162float(z[(size_t)s0 * OUT_DIM + lane]);
      const float z1 = __bfloat162float(z[(size_t)s1 * OUT_DIM + lane]);
      const float z2 = __bfloat162float(z[(size_t)s2 * OUT_DIM + lane]);
      const float z3 = __bfloat162float(z[(size_t)s3 * OUT_DIM + lane]);
      acc0 = fmaf(w0, z0, acc0);
      acc1 = fmaf(w1, z1, acc1);
      acc2 = fmaf(w2, z2, acc2);
      acc3 = fmaf(w3, z3, acc3);
    }
    for (; j < cnt; ++j) {
      const int sj = rlanei(s, j);
      const float wj = rlanef(w, j);
      acc0 = fmaf(wj, __bfloat162float(z[(size_t)sj * OUT_DIM + lane]), acc0);
    }
  }
  float acc = (acc0 + acc1) + (acc2 + acc3);
#pragma unroll
  for (int off = 32; off; off >>= 1) dsum += __shfl_xor(dsum, off, 64);

  const float h = acc / (dsum > 0.f ? dsum : 1.f);
  out[(size_t)node * OUT_DIM + lane] = h > 0.f ? h : expm1f(h);
}

// ---------------------------------------------------------------------------
extern "C" void kernel_launch(void* const* d_in, const int* in_sizes, int n_in,
                              void* d_out, int out_size, void* d_ws, size_t ws_size,
                              hipStream_t stream) {
  const float* feat  = (const float*)d_in[0];
  const float* fcw   = (const float*)d_in[1];
  const float* attnw = (const float*)d_in[2];
  const int* src     = (const int*)d_in[3];
  const int* dst     = (const int*)d_in[4];
  float* out = (float*)d_out;

  char* ws = (char*)d_ws;
  __hip_bfloat16* z = (__hip_bfloat16*)ws;
  ws += (size_t)N_NODES * OUT_DIM * sizeof(__hip_bfloat16);  // 6.4 MB
  float* asrc = (float*)ws;   ws += (size_t)N_NODES * sizeof(float);
  float* adst = (float*)ws;   ws += (size_t)N_NODES * sizeof(float);
  int* counts = (int*)ws;     ws += (size_t)N_NODES * sizeof(int);
  int* cursor = (int*)ws;     ws += (size_t)N_NODES * sizeof(int);
  int* offsets = (int*)ws;    ws += (size_t)(N_NODES + 4) * sizeof(int);  // padded
  int* bsum = (int*)ws;       ws += 64 * sizeof(int);
  int* bbase = (int*)ws;      ws += 64 * sizeof(int);
  int* ssorted = (int*)ws;    ws += (size_t)N_EDGES * sizeof(int);        // 3.2 MB

  hipMemsetAsync(counts, 0, (size_t)N_NODES * sizeof(int), stream);

  gat_z_hist<<<Z_BLOCKS + HIST_BLOCKS, 256, 0, stream>>>(feat, fcw, attnw, z,
                                                         asrc, adst, dst, counts);
  gat_scan_partial<<<N_SBLK, 256, 0, stream>>>(counts, bsum);
  gat_scan_base<<<1, 64, 0, stream>>>(bsum, bbase, offsets);
  gat_scan_final<<<N_SBLK, 256, 0, stream>>>(counts, bbase, offsets, cursor);
  gat_escatter<<<HIST_BLOCKS, 256, 0, stream>>>(src, dst, cursor, ssorted);
  gat_agg<<<(N_NODES * 64 + 255) / 256, 256, 0, stream>>>(z, asrc, adst, offsets, ssorted, out);
}

// Round 8
// 178.160 us; speedup vs baseline: 1.3120x; 1.1388x over previous
//
#include <hip/hip_runtime.h>
#include <hip/hip_bf16.h>

#define N_NODES 50000
#define N_EDGES 800000
#define IN_DIM 128
#define OUT_DIM 64
#define NEG_SLOPE 0.01f
#define NEG_INF (-3.0e38f)

#define N_I4 (N_NODES / 4)          // 12500 int4 elements
#define N_SBLK ((N_I4 + 255) / 256) // 49 scan blocks
#define N_STRIPS (N_NODES / 16)      // 3125 16-node MFMA strips
#define Z_BLOCKS ((N_STRIPS + 3) / 4) // 782 (4 waves/block, 1 strip/wave)
#define E_I4 (N_EDGES / 4)           // 200000
#define HIST_BLOCKS ((E_I4 + 255) / 256)

typedef __bf16 bf16x8 __attribute__((ext_vector_type(8)));
typedef float f32x4 __attribute__((ext_vector_type(4)));

__device__ __forceinline__ float rlanef(float v, int l) {
  return __uint_as_float(__builtin_amdgcn_readlane(__float_as_uint(v), l));
}
__device__ __forceinline__ int rlanei(int v, int l) {
  return __builtin_amdgcn_readlane(v, l);
}

__device__ __forceinline__ unsigned short f2bf_us(float f) {
  __hip_bfloat16 h = __float2bfloat16(f);  // RNE
  return *reinterpret_cast<unsigned short*>(&h);
}
__device__ __forceinline__ bf16x8 pack_bf16(float4 lo, float4 hi) {
  union { bf16x8 v; unsigned short u[8]; } r;
  r.u[0] = f2bf_us(lo.x); r.u[1] = f2bf_us(lo.y);
  r.u[2] = f2bf_us(lo.z); r.u[3] = f2bf_us(lo.w);
  r.u[4] = f2bf_us(hi.x); r.u[5] = f2bf_us(hi.y);
  r.u[6] = f2bf_us(hi.z); r.u[7] = f2bf_us(hi.w);
  return r.v;
}

// ---------------------------------------------------------------------------
// Stage 1 (fused). Blocks [0, Z_BLOCKS): MFMA z-GEMM (one 16-node strip per
// wave; layout comments in R7). Blocks [Z_BLOCKS,...): rank pass —
// rank[i] = atomicAdd(cursor[dst[i]], 1). Final cursor == per-dst counts
// (feeds the scan); rank lets the placement pass run WITHOUT atomics.
// ---------------------------------------------------------------------------
__global__ __launch_bounds__(256) void gat_z_hist(
    const float* __restrict__ feat, const float* __restrict__ fcw,
    const float* __restrict__ attnw, __hip_bfloat16* __restrict__ z,
    float* __restrict__ asrc, float* __restrict__ adst,
    const int* __restrict__ dst, int* __restrict__ cursor,
    int* __restrict__ rank) {
  if (blockIdx.x >= Z_BLOCKS) {
    int t = (blockIdx.x - Z_BLOCKS) * 256 + threadIdx.x;
    if (t < E_I4) {
      int4 d = ((const int4*)dst)[t];
      int4 r;
      r.x = atomicAdd(cursor + d.x, 1);
      r.y = atomicAdd(cursor + d.y, 1);
      r.z = atomicAdd(cursor + d.z, 1);
      r.w = atomicAdd(cursor + d.w, 1);
      ((int4*)rank)[t] = r;
    }
    return;
  }

  const int lane = threadIdx.x & 63;
  const int m = lane & 15;
  const int quad = lane >> 4;
  const int wv = blockIdx.x * 4 + (threadIdx.x >> 6);
  if (wv >= N_STRIPS) return;
  const int n0 = wv * 16;

  bf16x8 bfrag[4][4];
#pragma unroll
  for (int t = 0; t < 4; ++t) {
    const float* wr = fcw + (size_t)(m + 16 * t) * IN_DIM + quad * 8;
#pragma unroll
    for (int c = 0; c < 4; ++c) {
      float4 lo = *(const float4*)(wr + c * 32);
      float4 hi = *(const float4*)(wr + c * 32 + 4);
      bfrag[t][c] = pack_bf16(lo, hi);
    }
  }

  f32x4 acc[4] = {{0.f, 0.f, 0.f, 0.f}, {0.f, 0.f, 0.f, 0.f},
                  {0.f, 0.f, 0.f, 0.f}, {0.f, 0.f, 0.f, 0.f}};
  const float* ar = feat + (size_t)(n0 + m) * IN_DIM + quad * 8;
#pragma unroll
  for (int c = 0; c < 4; ++c) {
    float4 lo = *(const float4*)(ar + c * 32);
    float4 hi = *(const float4*)(ar + c * 32 + 4);
    const bf16x8 af = pack_bf16(lo, hi);
#pragma unroll
    for (int t = 0; t < 4; ++t)
      acc[t] = __builtin_amdgcn_mfma_f32_16x16x32_bf16(af, bfrag[t][c],
                                                       acc[t], 0, 0, 0);
  }

#pragma unroll
  for (int t = 0; t < 4; ++t)
#pragma unroll
    for (int r = 0; r < 4; ++r)
      z[(size_t)(n0 + quad * 4 + r) * OUT_DIM + m + 16 * t] =
          __float2bfloat16(acc[t][r]);

  float aws[4], awd[4];
#pragma unroll
  for (int t = 0; t < 4; ++t) {
    aws[t] = attnw[m + 16 * t];
    awd[t] = attnw[OUT_DIM + m + 16 * t];
  }
  float ps[4], pd[4];
#pragma unroll
  for (int r = 0; r < 4; ++r) {
    float s = 0.f, d = 0.f;
#pragma unroll
    for (int t = 0; t < 4; ++t) {
      s = fmaf(acc[t][r], aws[t], s);
      d = fmaf(acc[t][r], awd[t], d);
    }
    ps[r] = s;
    pd[r] = d;
  }
#pragma unroll
  for (int off = 1; off < 16; off <<= 1) {
#pragma unroll
    for (int r = 0; r < 4; ++r) {
      ps[r] += __shfl_xor(ps[r], off, 64);
      pd[r] += __shfl_xor(pd[r], off, 64);
    }
  }
  if (m == 0) {
#pragma unroll
    for (int r = 0; r < 4; ++r) {
      asrc[n0 + quad * 4 + r] = ps[r];
      adst[n0 + quad * 4 + r] = pd[r];
    }
  }
}

// ---------------------------------------------------------------------------
// Hierarchical exclusive scan over counts (== final cursor values).
// ---------------------------------------------------------------------------
__global__ __launch_bounds__(256) void gat_scan_partial(
    const int* __restrict__ counts, int* __restrict__ bsum) {
  const int lane = threadIdx.x & 63;
  const int wid = threadIdx.x >> 6;
  int i4 = blockIdx.x * 256 + threadIdx.x;
  int4 c = (i4 < N_I4) ? ((const int4*)counts)[i4] : make_int4(0, 0, 0, 0);
  int s = c.x + c.y + c.z + c.w;
#pragma unroll
  for (int off = 32; off; off >>= 1) s += __shfl_xor(s, off, 64);
  __shared__ int ws[4];
  if (lane == 0) ws[wid] = s;
  __syncthreads();
  if (threadIdx.x == 0) bsum[blockIdx.x] = ws[0] + ws[1] + ws[2] + ws[3];
}

__global__ __launch_bounds__(64) void gat_scan_base(
    const int* __restrict__ bsum, int* __restrict__ bbase,
    int* __restrict__ offsets) {
  const int t = threadIdx.x;
  int v = (t < N_SBLK) ? bsum[t] : 0;
  int incl = v;
#pragma unroll
  for (int off = 1; off < 64; off <<= 1) {
    int u = __shfl_up(incl, off, 64);
    if (t >= off) incl += u;
  }
  if (t < N_SBLK) bbase[t] = incl - v;
  if (t == 63) offsets[N_NODES] = incl;  // == N_EDGES
}

__global__ __launch_bounds__(256) void gat_scan_final(
    const int* __restrict__ counts, const int* __restrict__ bbase,
    int* __restrict__ offsets) {
  const int lane = threadIdx.x & 63;
  const int wid = threadIdx.x >> 6;
  int i4 = blockIdx.x * 256 + threadIdx.x;
  int4 c = (i4 < N_I4) ? ((const int4*)counts)[i4] : make_int4(0, 0, 0, 0);
  int s = c.x + c.y + c.z + c.w;
  int incl = s;
#pragma unroll
  for (int off = 1; off < 64; off <<= 1) {
    int u = __shfl_up(incl, off, 64);
    if (lane >= off) incl += u;
  }
  __shared__ int ws[4];
  if (lane == 63) ws[wid] = incl;
  __syncthreads();
  int wb = 0;
#pragma unroll
  for (int k = 0; k < 4; ++k)
    if (k < wid) wb += ws[k];
  int ex = bbase[blockIdx.x] + wb + (incl - s);
  int4 o;
  o.x = ex;
  o.y = o.x + c.x;
  o.z = o.y + c.y;
  o.w = o.z + c.z;
  if (i4 < N_I4) ((int4*)offsets)[i4] = o;
}

// ---------------------------------------------------------------------------
// Placement: ssorted[offsets[d] + rank] = src. NO atomics — plain stores.
// ---------------------------------------------------------------------------
__global__ __launch_bounds__(256) void gat_place(
    const int* __restrict__ src, const int* __restrict__ dst,
    const int* __restrict__ rank, const int* __restrict__ offsets,
    int* __restrict__ ssorted) {
  int t = blockIdx.x * blockDim.x + threadIdx.x;
  if (t >= E_I4) return;
  int4 s = ((const int4*)src)[t];
  int4 d = ((const int4*)dst)[t];
  int4 r = ((const int4*)rank)[t];
  ssorted[offsets[d.x] + r.x] = s.x;
  ssorted[offsets[d.y] + r.y] = s.y;
  ssorted[offsets[d.z] + r.z] = s.z;
  ssorted[offsets[d.w] + r.w] = s.w;
}

// ---------------------------------------------------------------------------
// Aggregation: one wave per dst node, online softmax. Gather phase processes
// 2 edges/iteration (half-wave each, lane -> 2 cols via uint=2×bf16 loads),
// 4 independent chains => 8 edges in flight. No atomics.
// ---------------------------------------------------------------------------
__global__ __launch_bounds__(256) void gat_agg(
    const __hip_bfloat16* __restrict__ zb, const float* __restrict__ asrc,
    const float* __restrict__ adst, const int* __restrict__ offsets,
    const int* __restrict__ ssorted, float* __restrict__ out) {
  const int lane = threadIdx.x & 63;
  const int cl = lane & 31;   // column pair: cols 2cl, 2cl+1
  const int half = lane >> 5; // 0: even edges, 1: odd edges
  const int node = (blockIdx.x * blockDim.x + threadIdx.x) >> 6;
  if (node >= N_NODES) return;
  const unsigned* __restrict__ zp = (const unsigned*)zb;  // 32 uints per row
  const int o0 = offsets[node];
  const int o1 = offsets[node + 1];
  if (o0 == o1) {  // no incoming edges: elu(0/1) = 0
    if (half == 0)
      *(float2*)(out + (size_t)node * OUT_DIM + 2 * cl) = make_float2(0.f, 0.f);
    return;
  }
  const float ad = adst[node];

  float m = NEG_INF, dsum = 0.f;
  float2 acc0 = {0.f, 0.f}, acc1 = {0.f, 0.f};
  float2 acc2 = {0.f, 0.f}, acc3 = {0.f, 0.f};

  for (int base = o0; base < o1; base += 64) {
    const int cnt = min(64, o1 - base);
    int s = 0;
    float ev = NEG_INF;
    if (lane < cnt) {
      s = ssorted[base + lane];
      float v = asrc[s] + ad;
      ev = v > 0.f ? v : NEG_SLOPE * v;
    }
    float cm = ev;
#pragma unroll
    for (int off = 32; off; off >>= 1) cm = fmaxf(cm, __shfl_xor(cm, off, 64));
    const float nm = fmaxf(m, cm);
    const float scale = __expf(m - nm);  // first chunk: exp(-inf) = 0
    dsum *= scale;
    acc0.x *= scale; acc0.y *= scale; acc1.x *= scale; acc1.y *= scale;
    acc2.x *= scale; acc2.y *= scale; acc3.x *= scale; acc3.y *= scale;
    m = nm;

    float w = (lane < cnt) ? __expf(ev - m) : 0.f;  // w=0 beyond cnt
    dsum += w;

    // 8 edges per iteration; out-of-range slots have w=0 (harmless z[0] load)
    for (int i = 0; i < cnt; i += 8) {
      int sa, sb; float wa, wb;
      sa = rlanei(s, i + 0); sb = rlanei(s, i + 1);
      wa = rlanef(w, i + 0); wb = rlanef(w, i + 1);
      const int s0 = half ? sb : sa; const float w0 = half ? wb : wa;
      sa = rlanei(s, i + 2); sb = rlanei(s, i + 3);
      wa = rlanef(w, i + 2); wb = rlanef(w, i + 3);
      const int s1 = half ? sb : sa; const float w1 = half ? wb : wa;
      sa = rlanei(s, i + 4); sb = rlanei(s, i + 5);
      wa = rlanef(w, i + 4); wb = rlanef(w, i + 5);
      const int s2 = half ? sb : sa; const float w2 = half ? wb : wa;
      sa = rlanei(s, i + 6); sb = rlanei(s, i + 7);
      wa = rlanef(w, i + 6); wb = rlanef(w, i + 7);
      const int s3 = half ? sb : sa; const float w3 = half ? wb : wa;

      const unsigned u0 = zp[(size_t)s0 * 32 + cl];
      const unsigned u1 = zp[(size_t)s1 * 32 + cl];
      const unsigned u2 = zp[(size_t)s2 * 32 + cl];
      const unsigned u3 = zp[(size_t)s3 * 32 + cl];

      acc0.x = fmaf(w0, __uint_as_float(u0 << 16), acc0.x);
      acc0.y = fmaf(w0, __uint_as_float(u0 & 0xffff0000u), acc0.y);
      acc1.x = fmaf(w1, __uint_as_float(u1 << 16), acc1.x);
      acc1.y = fmaf(w1, __uint_as_float(u1 & 0xffff0000u), acc1.y);
      acc2.x = fmaf(w2, __uint_as_float(u2 << 16), acc2.x);
      acc2.y = fmaf(w2, __uint_as_float(u2 & 0xffff0000u), acc2.y);
      acc3.x = fmaf(w3, __uint_as_float(u3 << 16), acc3.x);
      acc3.y = fmaf(w3, __uint_as_float(u3 & 0xffff0000u), acc3.y);
    }
  }
  float ax = (acc0.x + acc1.x) + (acc2.x + acc3.x);
  float ay = (acc0.y + acc1.y) + (acc2.y + acc3.y);
  ax += __shfl_xor(ax, 32, 64);  // combine even/odd-edge halves
  ay += __shfl_xor(ay, 32, 64);
#pragma unroll
  for (int off = 32; off; off >>= 1) dsum += __shfl_xor(dsum, off, 64);

  const float inv = 1.f / (dsum > 0.f ? dsum : 1.f);
  float hx = ax * inv, hy = ay * inv;
  hx = hx > 0.f ? hx : expm1f(hx);
  hy = hy > 0.f ? hy : expm1f(hy);
  if (half == 0)
    *(float2*)(out + (size_t)node * OUT_DIM + 2 * cl) = make_float2(hx, hy);
}

// ---------------------------------------------------------------------------
extern "C" void kernel_launch(void* const* d_in, const int* in_sizes, int n_in,
                              void* d_out, int out_size, void* d_ws, size_t ws_size,
                              hipStream_t stream) {
  const float* feat  = (const float*)d_in[0];
  const float* fcw   = (const float*)d_in[1];
  const float* attnw = (const float*)d_in[2];
  const int* src     = (const int*)d_in[3];
  const int* dst     = (const int*)d_in[4];
  float* out = (float*)d_out;

  char* ws = (char*)d_ws;
  __hip_bfloat16* z = (__hip_bfloat16*)ws;
  ws += (size_t)N_NODES * OUT_DIM * sizeof(__hip_bfloat16);  // 6.4 MB
  float* asrc = (float*)ws;   ws += (size_t)N_NODES * sizeof(float);
  float* adst = (float*)ws;   ws += (size_t)N_NODES * sizeof(float);
  int* cursor = (int*)ws;     ws += (size_t)N_NODES * sizeof(int);    // -> counts
  int* offsets = (int*)ws;    ws += (size_t)(N_NODES + 4) * sizeof(int);
  int* bsum = (int*)ws;       ws += 64 * sizeof(int);
  int* bbase = (int*)ws;      ws += 64 * sizeof(int);
  int* rank = (int*)ws;       ws += (size_t)N_EDGES * sizeof(int);    // 3.2 MB
  int* ssorted = (int*)ws;    ws += (size_t)N_EDGES * sizeof(int);    // 3.2 MB

  hipMemsetAsync(cursor, 0, (size_t)N_NODES * sizeof(int), stream);

  gat_z_hist<<<Z_BLOCKS + HIST_BLOCKS, 256, 0, stream>>>(
      feat, fcw, attnw, z, asrc, adst, dst, cursor, rank);
  gat_scan_partial<<<N_SBLK, 256, 0, stream>>>(cursor, bsum);
  gat_scan_base<<<1, 64, 0, stream>>>(bsum, bbase, offsets);
  gat_scan_final<<<N_SBLK, 256, 0, stream>>>(cursor, bbase, offsets);
  gat_place<<<HIST_BLOCKS, 256, 0, stream>>>(src, dst, rank, offsets, ssorted);
  gat_agg<<<(N_NODES * 64 + 255) / 256, 256, 0, stream>>>(z, asrc, adst,
                                                          offsets, ssorted, out);
}